// Round 16
// baseline (161.524 us; speedup 1.0000x reference)
//
#include <hip/hip_runtime.h>
#include <hip/hip_bf16.h>

#define NB 16
#define NQ 128
#define NK 512
#define DIN 256   // QS == KS == 256
#define NH 128
#define NDV 256

#define CSC 2.8853900817779268f   // 2*log2(e): tanh(x) = 1 - 2/(1 + 2^(CSC*x))

// Projection v3. Block = 32 rows of Q or K (grid: 64 Q-blocks + 256 K-blocks).
// Thread: h4 = tid&31 -> h = 4*h4..+3 ; rg = tid>>5 -> rows rg*4..+3.
// acc[4][4] = 16 fma per 16B W-load (4x R15's intensity). X tile 32KB LDS.
// K path stores KPT[b][h][k] transposed via padded LDS tile (stride 36 -> b128-aligned).
__global__ __launch_bounds__(256) void proj_both_kernel(
    const float* __restrict__ Q, const float* __restrict__ K,
    const float* __restrict__ Wq, const float* __restrict__ Wk,
    float* __restrict__ QP, float* __restrict__ KPT)
{
    __shared__ float Xl[32 * DIN];   // 32KB; reused as transpose tile for K path
    const int tid = threadIdx.x;
    int blk = blockIdx.x;
    const float* X; const float* W;
    int b, r0, isq;
    if (blk < 64) { isq = 1; b = blk >> 2; r0 = (blk & 3) * 32;
                    X = Q + ((size_t)b * NQ + r0) * DIN; W = Wq; }
    else { blk -= 64; isq = 0; b = blk >> 4; r0 = (blk & 15) * 32;
           X = K + ((size_t)b * NK + r0) * DIN; W = Wk; }

    {   // stage 32 rows: 2048 float4, coalesced
        const float4* Xg = (const float4*)X;
        float4* Xs = (float4*)Xl;
        #pragma unroll
        for (int i = 0; i < 8; ++i) Xs[tid + 256 * i] = Xg[tid + 256 * i];
    }
    __syncthreads();

    const int h4 = tid & 31;          // h = 4*h4
    const int rg = tid >> 5;          // rows rg*4 .. rg*4+3
    float4 acc[4];
    #pragma unroll
    for (int r = 0; r < 4; ++r) { acc[r].x = 0.f; acc[r].y = 0.f; acc[r].z = 0.f; acc[r].w = 0.f; }

    #pragma unroll 4
    for (int d = 0; d < DIN; d += 4) {
        float4 w0 = *(const float4*)&W[(d + 0) * NH + 4 * h4];   // 512B/half-wave coalesced
        float4 w1 = *(const float4*)&W[(d + 1) * NH + 4 * h4];
        float4 w2 = *(const float4*)&W[(d + 2) * NH + 4 * h4];
        float4 w3 = *(const float4*)&W[(d + 3) * NH + 4 * h4];
        #pragma unroll
        for (int r = 0; r < 4; ++r) {
            float4 x = *(const float4*)&Xl[(rg * 4 + r) * DIN + d];  // 2-addr broadcast, free
            acc[r].x += x.x * w0.x + x.y * w1.x + x.z * w2.x + x.w * w3.x;
            acc[r].y += x.x * w0.y + x.y * w1.y + x.z * w2.y + x.w * w3.y;
            acc[r].z += x.x * w0.z + x.y * w1.z + x.z * w2.z + x.w * w3.z;
            acc[r].w += x.x * w0.w + x.y * w1.w + x.z * w2.w + x.w * w3.w;
        }
    }
    #pragma unroll
    for (int r = 0; r < 4; ++r) {
        acc[r].x *= CSC; acc[r].y *= CSC; acc[r].z *= CSC; acc[r].w *= CSC;
    }

    if (isq) {
        #pragma unroll
        for (int r = 0; r < 4; ++r)
            *(float4*)&QP[((size_t)b * NQ + r0 + rg * 4 + r) * NH + 4 * h4] = acc[r];
    } else {
        float* T = Xl;                // [128 h][36] padded (36*4B % 16 == 0)
        __syncthreads();
        #pragma unroll
        for (int r = 0; r < 4; ++r) {
            T[(4 * h4 + 0) * 36 + rg * 4 + r] = acc[r].x;
            T[(4 * h4 + 1) * 36 + rg * 4 + r] = acc[r].y;
            T[(4 * h4 + 2) * 36 + rg * 4 + r] = acc[r].z;
            T[(4 * h4 + 3) * 36 + rg * 4 + r] = acc[r].w;
        }
        __syncthreads();
        #pragma unroll
        for (int i = 0; i < 4; ++i) {
            const int idx = tid + 256 * i;        // 0..1023
            const int h = idx >> 3, c8 = idx & 7; // 8 float4 per h row
            float4 v = *(const float4*)&T[h * 36 + c8 * 4];
            *(float4*)&KPT[((size_t)b * NH + h) * NK + r0 + c8 * 4] = v;
        }
    }
}

// Fused scores + masked softmax + attn@V.  Block = (b, 4 q rows), 512 thr = 8
// waves, grid 512. XCD swizzle: b = blk&15 -> all 32 blocks of batch b land on
// XCD b%8 (round-robin dispatch) -> KPT[b] (256KB) fetched once per XCD.
// LDS 18.5KB -> 4 blocks/CU (wave-limited, ~100% occupancy).
__global__ __launch_bounds__(512) void attn_fused_kernel(
    const float* __restrict__ QP, const float* __restrict__ KPT,
    const float* __restrict__ wv, const int* __restrict__ vlen,
    const float* __restrict__ V, float* __restrict__ OUT)
{
    __shared__ float qcl[4 * NH];        // 2KB   CSC-scaled q-proj
    __shared__ float wvl[NH];            // 0.5KB -2*wv
    __shared__ float sc[4][NK];          // 8KB   scores -> attn
    __shared__ float part[2][4][NDV];    // 8KB   [k-half][row][d]
    const int tid = threadIdx.x;
    const int b  = blockIdx.x & 15;      // XCD-local batch
    const int q0 = (blockIdx.x >> 4) * 4;

    qcl[tid] = QP[((size_t)b * NQ + q0) * NH + tid];
    if (tid < NH) wvl[tid] = -2.0f * wv[tid];
    __syncthreads();

    int vl = vlen[b];
    vl = vl < 1 ? 1 : (vl > NK ? NK : vl);

    // ---- scores: score'(r,k) = sum_h wvl[h]/(1 + 2^(qcl[r][h]+kpt[h][k]))
    {
        const float* kb = KPT + (size_t)b * NH * NK + tid;
        float a0 = 0.f, a1 = 0.f, a2 = 0.f, a3 = 0.f;
        #pragma unroll 4
        for (int h = 0; h < NH; ++h) {
            float kv = kb[(size_t)h * NK];   // coalesced 256B/wave
            float wq = wvl[h];               // broadcast
            float e0 = __builtin_amdgcn_exp2f(qcl[0 * NH + h] + kv);
            float e1 = __builtin_amdgcn_exp2f(qcl[1 * NH + h] + kv);
            float e2 = __builtin_amdgcn_exp2f(qcl[2 * NH + h] + kv);
            float e3 = __builtin_amdgcn_exp2f(qcl[3 * NH + h] + kv);
            a0 += wq * __builtin_amdgcn_rcpf(e0 + 1.0f);
            a1 += wq * __builtin_amdgcn_rcpf(e1 + 1.0f);
            a2 += wq * __builtin_amdgcn_rcpf(e2 + 1.0f);
            a3 += wq * __builtin_amdgcn_rcpf(e3 + 1.0f);
        }
        const bool vld = (tid < vl);
        sc[0][tid] = vld ? a0 : -1e6f;
        sc[1][tid] = vld ? a1 : -1e6f;
        sc[2][tid] = vld ? a2 : -1e6f;
        sc[3][tid] = vld ? a3 : -1e6f;
    }
    __syncthreads();

    // ---- masked softmax: wave w (0..3) owns row w
    const int w = tid >> 6, lane = tid & 63;
    if (w < 4) {
        float vals[8];
        float m = -3.0e38f;
        #pragma unroll
        for (int i = 0; i < 8; ++i) { vals[i] = sc[w][lane + 64 * i]; m = fmaxf(m, vals[i]); }
        #pragma unroll
        for (int off = 32; off; off >>= 1) m = fmaxf(m, __shfl_xor(m, off, 64));
        float s = 0.f;
        #pragma unroll
        for (int i = 0; i < 8; ++i) {
            vals[i] = __builtin_amdgcn_exp2f((vals[i] - m) * 1.4426950408889634f);
            s += vals[i];
        }
        #pragma unroll
        for (int off = 32; off; off >>= 1) s += __shfl_xor(s, off, 64);
        const float invs = 1.0f / s;   // s >= 1
        #pragma unroll
        for (int i = 0; i < 8; ++i) sc[w][lane + 64 * i] = vals[i] * invs;
    }
    __syncthreads();

    // ---- out partials: wave w -> row (w&3), k in [ (w>>2)*256, +256 )
    {
        const int row = w & 3, kh = w >> 2;
        float4 o = {0.f, 0.f, 0.f, 0.f};
        const float* vb = V + (size_t)b * NK * NDV + lane * 4;
        const int kb0 = kh * 256;
        #pragma unroll 4
        for (int kk = 0; kk < 256; ++kk) {
            const int k = kb0 + kk;
            float4 v4 = *(const float4*)(vb + (size_t)k * NDV);   // 1KB/wave coalesced
            const float p = sc[row][k];                           // broadcast
            o.x += p * v4.x; o.y += p * v4.y; o.z += p * v4.z; o.w += p * v4.w;
        }
        *(float4*)&part[kh][row][lane * 4] = o;
    }
    __syncthreads();

    // ---- reduce 2 partials, store coalesced
    if (tid < 256) {
        const int r = tid >> 6, d4 = tid & 63;
        float4 p0 = *(const float4*)&part[0][r][d4 * 4];
        float4 p1 = *(const float4*)&part[1][r][d4 * 4];
        float4 s;
        s.x = p0.x + p1.x; s.y = p0.y + p1.y; s.z = p0.z + p1.z; s.w = p0.w + p1.w;
        *(float4*)&OUT[((size_t)b * NQ + q0 + r) * NDV + d4 * 4] = s;
    }
}

extern "C" void kernel_launch(void* const* d_in, const int* in_sizes, int n_in,
                              void* d_out, int out_size, void* d_ws, size_t ws_size,
                              hipStream_t stream) {
    const float* queries = (const float*)d_in[0];  // [16,128,256] f32
    const float* keys    = (const float*)d_in[1];  // [16,512,256] f32
    const float* values  = (const float*)d_in[2];  // [16,512,256] f32
    const int*   vlen    = (const int*)d_in[3];    // [16] int32
    const float* Wq      = (const float*)d_in[4];  // [256,128] f32
    const float* Wk      = (const float*)d_in[5];  // [256,128] f32
    const float* wv      = (const float*)d_in[6];  // [128] f32
    float* out           = (float*)d_out;          // [16,128,256] f32

    float* qp  = (float*)d_ws;                     // QP  [16][128][128] = 1MB (CSC-scaled)
    float* kpt = qp + (size_t)NB * NQ * NH;        // KPT [16][128][512] = 4MB (CSC-scaled, transposed)

    proj_both_kernel<<<64 + 256, 256, 0, stream>>>(queries, keys, Wq, Wk, qp, kpt);
    attn_fused_kernel<<<NB * 32, 512, 0, stream>>>(qp, kpt, wv, vlen, values, out);
}

// Round 17
// 131.559 us; speedup vs baseline: 1.2278x; 1.2278x over previous
//
#include <hip/hip_runtime.h>
#include <hip/hip_bf16.h>

#define NB 16
#define NQ 128
#define NK 512
#define DIN 256   // QS == KS == 256
#define NH 128
#define NDV 256

#define CSC 2.8853900817779268f   // 2*log2(e): tanh(x) = 1 - 2/(1 + 2^(CSC*x))

// Projection v4: 2-deep software-pipelined W loads (3 groups x 4 float4 in
// flight; 64 fma per group covers L2 latency). Block = 32 rows (64 Q-blocks +
// 256 K-blocks). Thread: h4 = tid&31 -> h = 4*h4..+3 ; rg = tid>>5 -> rows
// rg*4..+3; acc[4][4] = 16 fma per 16B load. K path: transposed KPT store
// via padded LDS tile.
__global__ __launch_bounds__(256) void proj_both_kernel(
    const float* __restrict__ Q, const float* __restrict__ K,
    const float* __restrict__ Wq, const float* __restrict__ Wk,
    float* __restrict__ QP, float* __restrict__ KPT)
{
    __shared__ float Xl[32 * DIN];   // 32KB; reused as transpose tile for K path
    const int tid = threadIdx.x;
    int blk = blockIdx.x;
    const float* X; const float* W;
    int b, r0, isq;
    if (blk < 64) { isq = 1; b = blk >> 2; r0 = (blk & 3) * 32;
                    X = Q + ((size_t)b * NQ + r0) * DIN; W = Wq; }
    else { blk -= 64; isq = 0; b = blk >> 4; r0 = (blk & 15) * 32;
           X = K + ((size_t)b * NK + r0) * DIN; W = Wk; }

    {   // stage 32 rows: 2048 float4, coalesced
        const float4* Xg = (const float4*)X;
        float4* Xs = (float4*)Xl;
        #pragma unroll
        for (int i = 0; i < 8; ++i) Xs[tid + 256 * i] = Xg[tid + 256 * i];
    }
    __syncthreads();

    const int h4 = tid & 31;          // h = 4*h4
    const int rg = tid >> 5;          // rows rg*4 .. rg*4+3
    const float4* Wv = (const float4*)W;   // index d*32 + h4

    float4 acc[4];
    #pragma unroll
    for (int r = 0; r < 4; ++r) { acc[r].x = 0.f; acc[r].y = 0.f; acc[r].z = 0.f; acc[r].w = 0.f; }

    // 2-deep prefetch pipeline over 64 groups of 4 d-rows
    float4 w0 = Wv[0 * 32 + h4], w1 = Wv[1 * 32 + h4], w2 = Wv[2 * 32 + h4], w3 = Wv[3 * 32 + h4];
    float4 n0 = Wv[4 * 32 + h4], n1 = Wv[5 * 32 + h4], n2 = Wv[6 * 32 + h4], n3 = Wv[7 * 32 + h4];
    for (int d = 0; d < DIN; d += 4) {
        const int dp = (d + 8 < DIN) ? d + 8 : 0;     // harmless re-load at tail
        float4 m0 = Wv[(dp + 0) * 32 + h4];
        float4 m1 = Wv[(dp + 1) * 32 + h4];
        float4 m2 = Wv[(dp + 2) * 32 + h4];
        float4 m3 = Wv[(dp + 3) * 32 + h4];
        #pragma unroll
        for (int r = 0; r < 4; ++r) {
            float4 x = *(const float4*)&Xl[(rg * 4 + r) * DIN + d];  // broadcast
            acc[r].x += x.x * w0.x + x.y * w1.x + x.z * w2.x + x.w * w3.x;
            acc[r].y += x.x * w0.y + x.y * w1.y + x.z * w2.y + x.w * w3.y;
            acc[r].z += x.x * w0.z + x.y * w1.z + x.z * w2.z + x.w * w3.z;
            acc[r].w += x.x * w0.w + x.y * w1.w + x.z * w2.w + x.w * w3.w;
        }
        w0 = n0; w1 = n1; w2 = n2; w3 = n3;
        n0 = m0; n1 = m1; n2 = m2; n3 = m3;
    }
    #pragma unroll
    for (int r = 0; r < 4; ++r) {
        acc[r].x *= CSC; acc[r].y *= CSC; acc[r].z *= CSC; acc[r].w *= CSC;
    }

    if (isq) {
        #pragma unroll
        for (int r = 0; r < 4; ++r)
            *(float4*)&QP[((size_t)b * NQ + r0 + rg * 4 + r) * NH + 4 * h4] = acc[r];
    } else {
        float* T = Xl;                // [128 h][36] padded (36*4B % 16 == 0)
        __syncthreads();
        #pragma unroll
        for (int r = 0; r < 4; ++r) {
            T[(4 * h4 + 0) * 36 + rg * 4 + r] = acc[r].x;
            T[(4 * h4 + 1) * 36 + rg * 4 + r] = acc[r].y;
            T[(4 * h4 + 2) * 36 + rg * 4 + r] = acc[r].z;
            T[(4 * h4 + 3) * 36 + rg * 4 + r] = acc[r].w;
        }
        __syncthreads();
        #pragma unroll
        for (int i = 0; i < 4; ++i) {
            const int idx = tid + 256 * i;        // 0..1023
            const int h = idx >> 3, c8 = idx & 7; // 8 float4 per h row
            float4 v = *(const float4*)&T[h * 36 + c8 * 4];
            *(float4*)&KPT[((size_t)b * NH + h) * NK + r0 + c8 * 4] = v;
        }
    }
}

// Fused scores + masked softmax + attn@V.  Block = (b, 4 q rows), 512 thr = 8
// waves, grid 512. XCD swizzle: b = blk&15 -> all 32 blocks of batch b on one
// XCD -> KPT[b]+V[b] L2-resident (FETCH ~7MB, measured R16).
// Out: wave w covers 64-k slice for ALL 4 rows (V[b] read once per block);
// two-stage LDS reduce keeps part at 16KB -> LDS 26.5KB, 4 blocks/CU.
__global__ __launch_bounds__(512) void attn_fused_kernel(
    const float* __restrict__ QP, const float* __restrict__ KPT,
    const float* __restrict__ wv, const int* __restrict__ vlen,
    const float* __restrict__ V, float* __restrict__ OUT)
{
    __shared__ float qcl[4 * NH];        // 2KB   CSC-scaled q-proj
    __shared__ float wvl[NH];            // 0.5KB -2*wv
    __shared__ float sc[4][NK];          // 8KB   scores -> attn
    __shared__ float part[4][4][NDV];    // 16KB  [k-quarter][row][d]
    const int tid = threadIdx.x;
    const int b  = blockIdx.x & 15;      // XCD-local batch
    const int q0 = (blockIdx.x >> 4) * 4;

    qcl[tid] = QP[((size_t)b * NQ + q0) * NH + tid];
    if (tid < NH) wvl[tid] = -2.0f * wv[tid];
    __syncthreads();

    int vl = vlen[b];
    vl = vl < 1 ? 1 : (vl > NK ? NK : vl);

    // ---- scores: score'(r,k) = sum_h wvl[h]/(1 + 2^(qcl[r][h]+kpt[h][k]))
    // (true score minus sum(wv): softmax-invariant row shift)
    {
        const float* kb = KPT + (size_t)b * NH * NK + tid;
        float a0 = 0.f, a1 = 0.f, a2 = 0.f, a3 = 0.f;
        #pragma unroll 4
        for (int h = 0; h < NH; ++h) {
            float kv = kb[(size_t)h * NK];   // coalesced 2KB/block-row
            float wq = wvl[h];               // broadcast
            float e0 = __builtin_amdgcn_exp2f(qcl[0 * NH + h] + kv);
            float e1 = __builtin_amdgcn_exp2f(qcl[1 * NH + h] + kv);
            float e2 = __builtin_amdgcn_exp2f(qcl[2 * NH + h] + kv);
            float e3 = __builtin_amdgcn_exp2f(qcl[3 * NH + h] + kv);
            a0 += wq * __builtin_amdgcn_rcpf(e0 + 1.0f);
            a1 += wq * __builtin_amdgcn_rcpf(e1 + 1.0f);
            a2 += wq * __builtin_amdgcn_rcpf(e2 + 1.0f);
            a3 += wq * __builtin_amdgcn_rcpf(e3 + 1.0f);
        }
        const bool vld = (tid < vl);
        sc[0][tid] = vld ? a0 : -1e6f;
        sc[1][tid] = vld ? a1 : -1e6f;
        sc[2][tid] = vld ? a2 : -1e6f;
        sc[3][tid] = vld ? a3 : -1e6f;
    }
    __syncthreads();

    // ---- masked softmax: wave w (0..3) owns row w
    const int w = tid >> 6, lane = tid & 63;
    if (w < 4) {
        float vals[8];
        float m = -3.0e38f;
        #pragma unroll
        for (int i = 0; i < 8; ++i) { vals[i] = sc[w][lane + 64 * i]; m = fmaxf(m, vals[i]); }
        #pragma unroll
        for (int off = 32; off; off >>= 1) m = fmaxf(m, __shfl_xor(m, off, 64));
        float s = 0.f;
        #pragma unroll
        for (int i = 0; i < 8; ++i) {
            vals[i] = __builtin_amdgcn_exp2f((vals[i] - m) * 1.4426950408889634f);
            s += vals[i];
        }
        #pragma unroll
        for (int off = 32; off; off >>= 1) s += __shfl_xor(s, off, 64);
        const float invs = 1.0f / s;   // s >= 1
        #pragma unroll
        for (int i = 0; i < 8; ++i) sc[w][lane + 64 * i] = vals[i] * invs;
    }
    __syncthreads();

    // ---- out partials: wave w covers k in [w*64, w*64+64) for ALL 4 rows
    float4 o[4];
    #pragma unroll
    for (int r = 0; r < 4; ++r) { o[r].x = 0.f; o[r].y = 0.f; o[r].z = 0.f; o[r].w = 0.f; }
    {
        const float* vb = V + (size_t)b * NK * NDV + lane * 4;
        const int kb0 = w * 64;
        #pragma unroll 4
        for (int kk = 0; kk < 64; ++kk) {
            const int k = kb0 + kk;
            float4 v4 = *(const float4*)(vb + (size_t)k * NDV);   // 1KB/wave coalesced
            float p0 = sc[0][k], p1 = sc[1][k], p2 = sc[2][k], p3 = sc[3][k];
            o[0].x += p0 * v4.x; o[0].y += p0 * v4.y; o[0].z += p0 * v4.z; o[0].w += p0 * v4.w;
            o[1].x += p1 * v4.x; o[1].y += p1 * v4.y; o[1].z += p1 * v4.z; o[1].w += p1 * v4.w;
            o[2].x += p2 * v4.x; o[2].y += p2 * v4.y; o[2].z += p2 * v4.z; o[2].w += p2 * v4.w;
            o[3].x += p3 * v4.x; o[3].y += p3 * v4.y; o[3].z += p3 * v4.z; o[3].w += p3 * v4.w;
        }
    }
    // stage 1: waves 4-7 write partials
    if (w >= 4) {
        #pragma unroll
        for (int r = 0; r < 4; ++r) *(float4*)&part[w - 4][r][lane * 4] = o[r];
    }
    __syncthreads();
    // stage 2: waves 0-3 pair-combine and write
    if (w < 4) {
        #pragma unroll
        for (int r = 0; r < 4; ++r) {
            float4 t = *(const float4*)&part[w][r][lane * 4];
            o[r].x += t.x; o[r].y += t.y; o[r].z += t.z; o[r].w += t.w;
            *(float4*)&part[w][r][lane * 4] = o[r];
        }
    }
    __syncthreads();
    // stage 3: sum 4 k-quarter partials, store coalesced
    if (tid < 256) {
        const int r = tid >> 6, d4 = tid & 63;
        float4 s = {0.f, 0.f, 0.f, 0.f};
        #pragma unroll
        for (int p = 0; p < 4; ++p) {
            float4 q = *(const float4*)&part[p][r][d4 * 4];
            s.x += q.x; s.y += q.y; s.z += q.z; s.w += q.w;
        }
        *(float4*)&OUT[((size_t)b * NQ + q0 + r) * NDV + d4 * 4] = s;
    }
}

extern "C" void kernel_launch(void* const* d_in, const int* in_sizes, int n_in,
                              void* d_out, int out_size, void* d_ws, size_t ws_size,
                              hipStream_t stream) {
    const float* queries = (const float*)d_in[0];  // [16,128,256] f32
    const float* keys    = (const float*)d_in[1];  // [16,512,256] f32
    const float* values  = (const float*)d_in[2];  // [16,512,256] f32
    const int*   vlen    = (const int*)d_in[3];    // [16] int32
    const float* Wq      = (const float*)d_in[4];  // [256,128] f32
    const float* Wk      = (const float*)d_in[5];  // [256,128] f32
    const float* wv      = (const float*)d_in[6];  // [128] f32
    float* out           = (float*)d_out;          // [16,128,256] f32

    float* qp  = (float*)d_ws;                     // QP  [16][128][128] = 1MB (CSC-scaled)
    float* kpt = qp + (size_t)NB * NQ * NH;        // KPT [16][128][512] = 4MB (CSC-scaled, transposed)

    proj_both_kernel<<<64 + 256, 256, 0, stream>>>(queries, keys, Wq, Wk, qp, kpt);
    attn_fused_kernel<<<NB * 32, 512, 0, stream>>>(qp, kpt, wv, vlen, values, out);
}